// Round 5
// baseline (31724.719 us; speedup 1.0000x reference)
//
#include <hip/hip_runtime.h>
#include <stdint.h>

#define B_    64
#define EMB_  512
#define HID_  1024
#define V_    10000
#define T_    256
#define SOS_  1

typedef unsigned long long u64;
typedef unsigned int u32;

__device__ __forceinline__ float sig_(float v) { return 1.0f / (1.0f + __expf(-v)); }

// Packed activation layout: aP[k4][M][4] floats; element (k, m) at (k>>2)*M*4 + m*4 + (k&3).
// GEMM core: lane = row m (batch / vocab-row); wave accumulates NJ output columns over
// k-range [k0, k0+klen). A via per-lane float4 (coalesced, TD-efficient); W rows via
// wave-uniform scalar loads (s_load_dwordx8 expected: jbase/k uniform).
template<int NJ>
__device__ __forceinline__ void gemm_wave(
    const float4* __restrict__ aP4, int am, int abase, int b,
    const float* __restrict__ W, int ldk, int jbase,
    int k0, int klen, float* __restrict__ acc)
{
  const float* __restrict__ wr = W + (size_t)jbase * ldk + k0;
  const float4* __restrict__ ap = aP4 + (size_t)(k0 >> 2) * am + abase + b;
  float4 a0 = ap[0];
  float4 a1 = ap[am];
  for (int kk = 0; kk + 8 < klen; kk += 8) {
    const float4 n0 = ap[2 * am];
    const float4 n1 = ap[3 * am];
    ap += 2 * am;
#pragma unroll
    for (int j = 0; j < NJ; ++j) {
      const float* __restrict__ w = wr + (size_t)j * ldk + kk;
      float s = acc[j];
      s = fmaf(a0.x, w[0], s); s = fmaf(a0.y, w[1], s);
      s = fmaf(a0.z, w[2], s); s = fmaf(a0.w, w[3], s);
      s = fmaf(a1.x, w[4], s); s = fmaf(a1.y, w[5], s);
      s = fmaf(a1.z, w[6], s); s = fmaf(a1.w, w[7], s);
      acc[j] = s;
    }
    a0 = n0; a1 = n1;
  }
  {
    const int kk = klen - 8;
#pragma unroll
    for (int j = 0; j < NJ; ++j) {
      const float* __restrict__ w = wr + (size_t)j * ldk + kk;
      float s = acc[j];
      s = fmaf(a0.x, w[0], s); s = fmaf(a0.y, w[1], s);
      s = fmaf(a0.z, w[2], s); s = fmaf(a0.w, w[3], s);
      s = fmaf(a1.x, w[4], s); s = fmaf(a1.y, w[5], s);
      s = fmaf(a1.z, w[6], s); s = fmaf(a1.w, w[7], s);
      acc[j] = s;
    }
  }
}

// init: pack encoder final states into h0P/h1P; seed token = SOS
__global__ __launch_bounds__(256) void k_init(const float* __restrict__ efs,
                                              float* __restrict__ h0Pf,
                                              float* __restrict__ h1Pf,
                                              u64* __restrict__ part) {
  const int idx = blockIdx.x * 256 + threadIdx.x;   // 65536
  const int b = idx >> 10, k = idx & 1023;
  const int pa = (k >> 2) * 256 + b * 4 + (k & 3);
  h0Pf[pa] = efs[(size_t)b * HID_ + k];
  h1Pf[pa] = efs[(size_t)B_ * HID_ + (size_t)b * HID_ + k];
  if (idx < 64) part[idx] = (u64)(0xFFFFFFFFu - (u32)SOS_);
}

// T1: embP[k4][10000][4] = relu(emb), packed (once per launch, fast path)
__global__ __launch_bounds__(256) void k_t1(const float* __restrict__ emb,
                                            float4* __restrict__ embP4) {
  const int idx = blockIdx.x * 256 + threadIdx.x;   // 10000*128
  const int v = idx >> 7, k4 = idx & 127;
  float4 x = reinterpret_cast<const float4*>(emb)[(size_t)v * 128 + k4];
  x.x = fmaxf(x.x, 0.f); x.y = fmaxf(x.y, 0.f);
  x.z = fmaxf(x.z, 0.f); x.w = fmaxf(x.w, 0.f);
  embP4[(size_t)k4 * V_ + v] = x;
}

// T2: giET[3072][10000] = relu(emb) @ Wih0^T + bih0  (once per launch, fast path)
__global__ __launch_bounds__(1024) void k_t2(const float4* __restrict__ embP4,
                                             const float* __restrict__ Wih0,
                                             const float* __restrict__ bih0,
                                             float* __restrict__ giET) {
  __shared__ float ldsP[16 * 8 * 64];
  const int tid = threadIdx.x, v = tid & 63;
  const int wv = __builtin_amdgcn_readfirstlane(tid >> 6);   // 0..15
  const int wg = blockIdx.x;
  const int vb = wg % 157, cb = wg / 157;                    // 157 x 96
  const int v0 = vb * 64, c0 = cb * 32;
  const int jg = wv >> 2, q = wv & 3;
  const int jbase = __builtin_amdgcn_readfirstlane(c0 + jg * 8);
  float acc[8] = {0, 0, 0, 0, 0, 0, 0, 0};
  gemm_wave<8>(embP4, V_, v0, v, Wih0, EMB_, jbase, q * 128, 128, acc);
#pragma unroll
  for (int j = 0; j < 8; ++j) ldsP[(wv * 8 + j) * 64 + v] = acc[j];
  __syncthreads();
  if (v0 + v < V_) {
    const int g0 = tid >> 6;   // 0..15
#pragma unroll
    for (int h = 0; h < 2; ++h) {
      const int j32 = g0 + h * 16;
      const int jg2 = j32 >> 3, j8 = j32 & 7;
      float s = bih0[c0 + j32];
#pragma unroll
      for (int q2 = 0; q2 < 4; ++q2) s += ldsP[((jg2 * 4 + q2) * 8 + j8) * 64 + v];
      giET[(size_t)(c0 + j32) * V_ + v0 + v] = s;
    }
  }
}

// F0 (fallback): xP[k4][64][4] = relu(emb[tok[b]])
__global__ __launch_bounds__(256) void k_f0(const u64* __restrict__ part,
                                            const float* __restrict__ emb,
                                            float4* __restrict__ xP4) {
  const int tid = threadIdx.x;
  const int b = tid >> 2, kq = tid & 3;
  const int tok = (int)(0xFFFFFFFFu - (u32)(part[b] & 0xFFFFFFFFull));
  const float4* e4 = reinterpret_cast<const float4*>(emb) + (size_t)tok * 128;
#pragma unroll 4
  for (int i = 0; i < 32; ++i) {
    const int k4 = kq * 32 + i;
    float4 x = e4[k4];
    x.x = fmaxf(x.x, 0.f); x.y = fmaxf(x.y, 0.f);
    x.z = fmaxf(x.z, 0.f); x.w = fmaxf(x.w, 0.f);
    xP4[k4 * 64 + b] = x;
  }
}

// F1 (fallback): gi0T[3][1024][64] = xP @ Wih0^T + bih0
__global__ __launch_bounds__(768) void k_f1(const float4* __restrict__ xP4,
                                            const float* __restrict__ Wih0,
                                            const float* __restrict__ bih0,
                                            float* __restrict__ gi0T) {
  __shared__ float ldsP[12 * 4 * 64];
  const int tid = threadIdx.x, b = tid & 63;
  const int wv = __builtin_amdgcn_readfirstlane(tid >> 6);
  const int c0 = __builtin_amdgcn_readfirstlane((int)blockIdx.x * 4);
  const int g = wv >> 2, q = wv & 3;
  const int jbase = __builtin_amdgcn_readfirstlane(g * HID_ + c0);
  float acc[4] = {0, 0, 0, 0};
  gemm_wave<4>(xP4, 64, 0, b, Wih0, EMB_, jbase, q * 128, 128, acc);
#pragma unroll
  for (int j = 0; j < 4; ++j) ldsP[(wv * 4 + j) * 64 + b] = acc[j];
  __syncthreads();
  if (tid < 256) {
    const int c4 = tid >> 6, c = c0 + c4;
#pragma unroll
    for (int g2 = 0; g2 < 3; ++g2) {
      float s = bih0[g2 * HID_ + c];
#pragma unroll
      for (int q2 = 0; q2 < 4; ++q2) s += ldsP[((g2 * 4 + q2) * 4 + c4) * 64 + b];
      gi0T[(g2 * HID_ + c) * 64 + b] = s;
    }
  }
}

// P1: wg<256: gh0 = h0@Whh0^T (+GRU0 combine with gi0 gather -> h0nP)
//     wg>=256: gh1T = h1@Whh1^T + bhh1
__global__ __launch_bounds__(768) void k_p1(
    const u64* __restrict__ part, const float* __restrict__ giET,
    const float* __restrict__ gi0T, int gmode,
    const float* __restrict__ h0Pf, const float* __restrict__ h1Pf,
    const float* __restrict__ Whh0, const float* __restrict__ Whh1,
    const float* __restrict__ bhh0, const float* __restrict__ bhh1,
    float* __restrict__ h0nPf, float* __restrict__ gh1T) {
  __shared__ float ldsP[12 * 4 * 64];
  __shared__ int tokL[64];
  const int tid = threadIdx.x, b = tid & 63;
  const int wv = __builtin_amdgcn_readfirstlane(tid >> 6);
  const int wg = blockIdx.x;
  if (tid < 64) tokL[tid] = (int)(0xFFFFFFFFu - (u32)(part[tid] & 0xFFFFFFFFull));
  const bool is0 = wg < 256;
  const int c0 = __builtin_amdgcn_readfirstlane((is0 ? wg : wg - 256) * 4);
  const int g = wv >> 2, q = wv & 3;
  const int jbase = __builtin_amdgcn_readfirstlane(g * HID_ + c0);
  float acc[4] = {0, 0, 0, 0};
  gemm_wave<4>(reinterpret_cast<const float4*>(is0 ? h0Pf : h1Pf), 64, 0, b,
               is0 ? Whh0 : Whh1, HID_, jbase, q * 256, 256, acc);
#pragma unroll
  for (int j = 0; j < 4; ++j) ldsP[(wv * 4 + j) * 64 + b] = acc[j];
  __syncthreads();
  if (tid < 256) {
    const int c4 = tid >> 6, c = c0 + c4;
    float s0 = 0.f, s1 = 0.f, s2 = 0.f;
#pragma unroll
    for (int q2 = 0; q2 < 4; ++q2) {
      s0 += ldsP[((0 * 4 + q2) * 4 + c4) * 64 + b];
      s1 += ldsP[((1 * 4 + q2) * 4 + c4) * 64 + b];
      s2 += ldsP[((2 * 4 + q2) * 4 + c4) * 64 + b];
    }
    if (is0) {
      float gr, gz, gn;
      if (gmode) {
        const int tk = tokL[b];
        gr = giET[(size_t)(0 * HID_ + c) * V_ + tk];
        gz = giET[(size_t)(1 * HID_ + c) * V_ + tk];
        gn = giET[(size_t)(2 * HID_ + c) * V_ + tk];
      } else {
        gr = gi0T[(0 * HID_ + c) * 64 + b];
        gz = gi0T[(1 * HID_ + c) * 64 + b];
        gn = gi0T[(2 * HID_ + c) * 64 + b];
      }
      const float hr = s0 + bhh0[c], hz = s1 + bhh0[HID_ + c], hn = s2 + bhh0[2 * HID_ + c];
      const float r = sig_(gr + hr), z = sig_(gz + hz);
      const float n = tanhf(gn + r * hn);
      const int pa = (c >> 2) * 256 + b * 4 + (c & 3);
      h0nPf[pa] = (1.f - z) * n + z * h0Pf[pa];
    } else {
      gh1T[(0 * HID_ + c) * 64 + b] = s0 + bhh1[c];
      gh1T[(1 * HID_ + c) * 64 + b] = s1 + bhh1[HID_ + c];
      gh1T[(2 * HID_ + c) * 64 + b] = s2 + bhh1[2 * HID_ + c];
    }
  }
}

// P2: gi1 = h0n@Wih1^T -> GRU1 combine with gh1T -> h1nP ; wg0 resets argmax acc
__global__ __launch_bounds__(768) void k_p2(
    const float* __restrict__ h0nPf, const float* __restrict__ gh1T,
    const float* __restrict__ h1Pf, const float* __restrict__ Wih1,
    const float* __restrict__ bih1, float* __restrict__ h1nPf,
    u64* __restrict__ part) {
  __shared__ float ldsP[12 * 4 * 64];
  const int tid = threadIdx.x, b = tid & 63;
  const int wv = __builtin_amdgcn_readfirstlane(tid >> 6);
  const int c0 = __builtin_amdgcn_readfirstlane((int)blockIdx.x * 4);
  if (blockIdx.x == 0 && tid < 64) part[tid] = 0ull;
  const int g = wv >> 2, q = wv & 3;
  const int jbase = __builtin_amdgcn_readfirstlane(g * HID_ + c0);
  float acc[4] = {0, 0, 0, 0};
  gemm_wave<4>(reinterpret_cast<const float4*>(h0nPf), 64, 0, b,
               Wih1, HID_, jbase, q * 256, 256, acc);
#pragma unroll
  for (int j = 0; j < 4; ++j) ldsP[(wv * 4 + j) * 64 + b] = acc[j];
  __syncthreads();
  if (tid < 256) {
    const int c4 = tid >> 6, c = c0 + c4;
    float s0 = 0.f, s1 = 0.f, s2 = 0.f;
#pragma unroll
    for (int q2 = 0; q2 < 4; ++q2) {
      s0 += ldsP[((0 * 4 + q2) * 4 + c4) * 64 + b];
      s1 += ldsP[((1 * 4 + q2) * 4 + c4) * 64 + b];
      s2 += ldsP[((2 * 4 + q2) * 4 + c4) * 64 + b];
    }
    const float gr = s0 + bih1[c], gz = s1 + bih1[HID_ + c], gn = s2 + bih1[2 * HID_ + c];
    const float hr = gh1T[(0 * HID_ + c) * 64 + b];
    const float hz = gh1T[(1 * HID_ + c) * 64 + b];
    const float hn = gh1T[(2 * HID_ + c) * 64 + b];
    const float r = sig_(gr + hr), z = sig_(gz + hz);
    const float n = tanhf(gn + r * hn);
    const int pa = (c >> 2) * 256 + b * 4 + (c & 3);
    h1nPf[pa] = (1.f - z) * n + z * h1Pf[pa];
  }
}

// P3: hidP = relu(h1n @ pW1^T + pb1)
__global__ __launch_bounds__(512) void k_p3(
    const float* __restrict__ h1nPf, const float* __restrict__ pW1,
    const float* __restrict__ pb1, float* __restrict__ hidPf) {
  __shared__ float ldsP[8 * 4 * 64];
  const int tid = threadIdx.x, b = tid & 63;
  const int q = __builtin_amdgcn_readfirstlane(tid >> 6);   // 0..7
  const int c0 = __builtin_amdgcn_readfirstlane((int)blockIdx.x * 4);
  float acc[4] = {0, 0, 0, 0};
  gemm_wave<4>(reinterpret_cast<const float4*>(h1nPf), 64, 0, b,
               pW1, HID_, c0, q * 128, 128, acc);
#pragma unroll
  for (int j = 0; j < 4; ++j) ldsP[(q * 4 + j) * 64 + b] = acc[j];
  __syncthreads();
  if (tid < 256) {
    const int c4 = tid >> 6, c = c0 + c4;
    float s = pb1[c];
#pragma unroll
    for (int q2 = 0; q2 < 8; ++q2) s += ldsP[(q2 * 4 + c4) * 64 + b];
    hidPf[(c >> 2) * 256 + b * 4 + (c & 3)] = fmaxf(s, 0.f);
  }
}

// P4: 8 logit columns per WG = hid @ pW2^T + pb2; coalesced store; argmax atomicMax
__global__ __launch_bounds__(256) void k_p4(
    const float* __restrict__ hidPf, const float* __restrict__ pW2,
    const float* __restrict__ pb2, float* __restrict__ out,
    u64* __restrict__ part, int step) {
  __shared__ float ldsP[4 * 8 * 64];
  __shared__ float ldsO[8 * 64];
  __shared__ u64 ldsM[4 * 64];
  const int tid = threadIdx.x, b = tid & 63;
  const int q = __builtin_amdgcn_readfirstlane(tid >> 6);   // 0..3
  const int c0 = __builtin_amdgcn_readfirstlane((int)blockIdx.x * 8);
  float acc[8] = {0, 0, 0, 0, 0, 0, 0, 0};
  gemm_wave<8>(reinterpret_cast<const float4*>(hidPf), 64, 0, b,
               pW2, HID_, c0, q * 256, 256, acc);
#pragma unroll
  for (int j = 0; j < 8; ++j) ldsP[(q * 8 + j) * 64 + b] = acc[j];
  __syncthreads();
  {
    const int cp = tid >> 6;   // 0..3
    u64 pk = 0ull;
#pragma unroll
    for (int h = 0; h < 2; ++h) {
      const int cc = cp * 2 + h;
      float s = pb2[c0 + cc];
#pragma unroll
      for (int q2 = 0; q2 < 4; ++q2) s += ldsP[(q2 * 8 + cc) * 64 + b];
      ldsO[cc * 64 + b] = s;
      u32 kb = __float_as_uint(s);
      kb = (kb & 0x80000000u) ? ~kb : (kb | 0x80000000u);
      const u64 p = ((u64)kb << 32) | (u64)(0xFFFFFFFFu - (u32)(c0 + cc));
      if (p > pk) pk = p;
    }
    ldsM[cp * 64 + b] = pk;
  }
  __syncthreads();
  // coalesced-ish logits store: 8 consecutive floats per batch row
#pragma unroll
  for (int h = 0; h < 2; ++h) {
    const int i = h * 256 + tid;
    const int bb = i >> 3, cc = i & 7;
    out[((size_t)bb * T_ + step) * V_ + c0 + cc] = ldsO[cc * 64 + bb];
  }
  if (tid < 64) {
    u64 pk = ldsM[tid];
#pragma unroll
    for (int i = 1; i < 4; ++i) {
      const u64 o = ldsM[i * 64 + tid];
      if (o > pk) pk = o;
    }
    atomicMax(&part[tid], pk);
  }
}

extern "C" void kernel_launch(void* const* d_in, const int* in_sizes, int n_in,
                              void* d_out, int out_size, void* d_ws, size_t ws_size,
                              hipStream_t stream) {
  (void)in_sizes; (void)n_in; (void)out_size;
  const float* efs  = (const float*)d_in[1];
  const float* embW = (const float*)d_in[2];
  const float* Wih0 = (const float*)d_in[3];
  const float* Whh0 = (const float*)d_in[4];
  const float* bih0 = (const float*)d_in[5];
  const float* bhh0 = (const float*)d_in[6];
  const float* Wih1 = (const float*)d_in[7];
  const float* Whh1 = (const float*)d_in[8];
  const float* bih1 = (const float*)d_in[9];
  const float* bhh1 = (const float*)d_in[10];
  const float* pW1  = (const float*)d_in[11];
  const float* pb1  = (const float*)d_in[12];
  const float* pW2  = (const float*)d_in[13];
  const float* pb2  = (const float*)d_in[14];
  float* out = (float*)d_out;

  float* ws = (float*)d_ws;
  float* h0Pa = ws;                       // 65536
  float* h0Pb = ws + 65536;
  float* h1Pa = ws + 131072;
  float* h1Pb = ws + 196608;
  float* hidP = ws + 262144;              // 65536
  float* gh1T = ws + 327680;              // 196608
  float* gi0T = ws + 524288;              // 196608 (fallback)
  float* xP   = ws + 720896;              // 32768  (fallback)
  u64*   part = (u64*)(ws + 753664);      // 64 u64 = 128 floats
  float* embP = ws + 753792;              // 5,120,000 (fast)
  float* giET = ws + 5873792;             // 30,720,000 (fast)
  const size_t need_fast = (size_t)36593792 * 4;
  const int fast = ws_size >= need_fast ? 1 : 0;

  k_init<<<dim3(256), dim3(256), 0, stream>>>(efs, h0Pa, h1Pa, part);
  if (fast) {
    k_t1<<<dim3(5000), dim3(256), 0, stream>>>(embW, (float4*)embP);
    k_t2<<<dim3(15072), dim3(1024), 0, stream>>>((const float4*)embP, Wih0, bih0, giET);
  }
  for (int t = 0; t < T_; ++t) {
    const float* h0c = (t & 1) ? h0Pb : h0Pa;
    float*       h0n = (t & 1) ? h0Pa : h0Pb;
    const float* h1c = (t & 1) ? h1Pb : h1Pa;
    float*       h1n = (t & 1) ? h1Pa : h1Pb;
    if (!fast) {
      k_f0<<<dim3(1), dim3(256), 0, stream>>>(part, embW, (float4*)xP);
      k_f1<<<dim3(256), dim3(768), 0, stream>>>((const float4*)xP, Wih0, bih0, gi0T);
    }
    k_p1<<<dim3(512), dim3(768), 0, stream>>>(part, giET, gi0T, fast, h0c, h1c,
                                              Whh0, Whh1, bhh0, bhh1, h0n, gh1T);
    k_p2<<<dim3(256), dim3(768), 0, stream>>>(h0n, gh1T, h1c, Wih1, bih1, h1n, part);
    k_p3<<<dim3(256), dim3(512), 0, stream>>>(h1n, pW1, pb1, hidP);
    k_p4<<<dim3(1250), dim3(256), 0, stream>>>(hidP, pW2, pb2, out, part, t);
  }
}

// Round 6
// 27388.074 us; speedup vs baseline: 1.1583x; 1.1583x over previous
//
#include <hip/hip_runtime.h>
#include <stdint.h>

#define T_   256
#define V_   10000
#define SOS_ 1

typedef unsigned long long u64;
typedef unsigned int u32;
typedef unsigned short u16;
typedef _Float16 h8 __attribute__((ext_vector_type(8)));
typedef float f32x4 __attribute__((ext_vector_type(4)));

__device__ __forceinline__ float sig_(float v){ return 1.f/(1.f+__expf(-v)); }

__device__ __forceinline__ u16 h2u(_Float16 h){ union{ _Float16 h; u16 u; } x; x.h=h; return x.u; }

// split f32 -> fp16 hi + fp16 lo*2^11 (lo pre-scaled so it stays normal)
__device__ __forceinline__ void cvt8(const float* v, h8& hi, h8& lo){
#pragma unroll
  for(int j=0;j<8;++j){
    _Float16 h = (_Float16)v[j];
    hi[j] = h;
    lo[j] = (_Float16)((v[j] - (float)h) * 2048.f);
  }
}

// 3-pass split-fp16 MFMA: a0 += Ahi*Whi ; ax += Alo2k*Whi + Ahi*Wlo2k
__device__ __forceinline__ void mm3(h8 ah, h8 al, h8 wh, h8 wl, f32x4& a0, f32x4& ax){
  a0 = __builtin_amdgcn_mfma_f32_16x16x32_f16(ah, wh, a0, 0,0,0);
  ax = __builtin_amdgcn_mfma_f32_16x16x32_f16(al, wh, ax, 0,0,0);
  ax = __builtin_amdgcn_mfma_f32_16x16x32_f16(ah, wl, ax, 0,0,0);
}

template<int NT>
__device__ __forceinline__ void zacc(f32x4 (&a0)[4][NT], f32x4 (&ax)[4][NT]){
  f32x4 z = {0.f,0.f,0.f,0.f};
#pragma unroll
  for(int m=0;m<4;++m)
#pragma unroll
    for(int n=0;n<NT;++n){ a0[m][n]=z; ax[m][n]=z; }
}

// A frags: actF[(m*32+ks)*2+hl][512]  (hl: 0=hi,1=lo2k), lane l gets 8 u16 at l*8.
// W frags: wF  [(tile*32+ks)*2+hl][512]
template<int NT, int TS>
__device__ __forceinline__ void gemm_run(const u16* __restrict__ actF,
                                         const u16* __restrict__ wF,
                                         int tbase, int ks0, int nks, int l,
                                         f32x4 (&a0)[4][NT], f32x4 (&ax)[4][NT]){
  for(int ks = ks0; ks < ks0 + nks; ++ks){
    h8 Ah[4], Al[4];
#pragma unroll
    for(int m=0;m<4;++m){
      const u16* ab = actF + ((size_t)(m*32 + ks)*2)*512 + l*8;
      Ah[m] = *reinterpret_cast<const h8*>(ab);
      Al[m] = *reinterpret_cast<const h8*>(ab + 512);
    }
#pragma unroll
    for(int n=0;n<NT;++n){
      const u16* wb = wF + ((size_t)((tbase + n*TS)*32 + ks)*2)*512 + l*8;
      h8 Wh = *reinterpret_cast<const h8*>(wb);
      h8 Wl = *reinterpret_cast<const h8*>(wb + 512);
#pragma unroll
      for(int m=0;m<4;++m) mm3(Ah[m], Al[m], Wh, Wl, a0[m][n], ax[m][n]);
    }
  }
}

// collapse split-acc and write this wave's C tile to LDS [wv][m][n][row16][col16]
template<int NT>
__device__ __forceinline__ void to_lds(float* lds, int wv, int l,
                                       f32x4 (&a0)[4][NT], f32x4 (&ax)[4][NT]){
#pragma unroll
  for(int m=0;m<4;++m)
#pragma unroll
    for(int n=0;n<NT;++n)
#pragma unroll
      for(int r=0;r<4;++r){
        float v = a0[m][n][r] + ax[m][n][r]*(1.f/2048.f);
        lds[ ((((wv*4+m)*NT+n)*16) + ((l>>4)*4 + r))*16 + (l&15) ] = v;
      }
}

__device__ __forceinline__ float red4(const float* lds, int nt, int m, int n, int r16, int c16){
  int base = ((m*nt + n)*16 + r16)*16 + c16;
  int strd = 4*nt*256;
  return lds[base] + lds[base+strd] + lds[base+2*strd] + lds[base+3*strd];
}

// store one activation element into a frag buffer (hi + lo2k)
__device__ __forceinline__ void store_frag(u16* __restrict__ F, int b, int c, float v){
  int m16 = b>>4, ks = c>>5, fl = (b&15) + 16*((c>>3)&3), j = c&7;
  size_t base = ((size_t)(m16*32 + ks)*2)*512 + fl*8 + j;
  _Float16 h = (_Float16)v;
  F[base]       = h2u(h);
  F[base + 512] = h2u((_Float16)((v - (float)h)*2048.f));
}

// ---- one-time: weight -> fragment conversion --------------------------------
__global__ __launch_bounds__(256) void k_wcvt(const float* __restrict__ W, int N, int K, int KS,
                                              u16* __restrict__ dst){
  const int f = blockIdx.x*4 + (threadIdx.x>>6);
  const int l = threadIdx.x & 63;
  const int tile = f / KS, ks = f - tile*KS;
  const int row = tile*16 + (l&15);
  const int kb  = ks*32 + (l>>4)*8;
  float v[8];
  if(row < N){
    float4 v0 = *reinterpret_cast<const float4*>(W + (size_t)row*K + kb);
    float4 v1 = *reinterpret_cast<const float4*>(W + (size_t)row*K + kb + 4);
    v[0]=v0.x; v[1]=v0.y; v[2]=v0.z; v[3]=v0.w;
    v[4]=v1.x; v[5]=v1.y; v[6]=v1.z; v[7]=v1.w;
  } else {
#pragma unroll
    for(int j=0;j<8;++j) v[j]=0.f;
  }
  h8 hi, lo; cvt8(v, hi, lo);
  *reinterpret_cast<h8*>(dst + (size_t)f*1024 + l*8)       = hi;
  *reinterpret_cast<h8*>(dst + (size_t)f*1024 + 512 + l*8) = lo;
}

// ---- init: states -> mirrors + frags, seed token ----------------------------
__global__ __launch_bounds__(256) void k_init(const float* __restrict__ efs,
                                              float* __restrict__ h0T, float* __restrict__ h1T,
                                              u16* __restrict__ h0F, u16* __restrict__ h1F,
                                              u64* __restrict__ part){
  const int idx = blockIdx.x*256 + threadIdx.x;  // 65536 = 64b x 1024k
  const int b = idx >> 10, k = idx & 1023;
  const float v0 = efs[idx];
  const float v1 = efs[65536 + idx];
  h0T[k*64 + b] = v0;
  h1T[k*64 + b] = v1;
  store_frag(h0F, b, k, v0);
  store_frag(h1F, b, k, v1);
  if(idx < 64) part[idx] = (u64)(0xFFFFFFFFu - (u32)SOS_);
}

// ---- P1: WGs 0..63: GRU0 (gi0 from emb on-the-fly + gh0) -> h0n
//          WGs 64..127: gh1 = h1@Whh1^T + bhh1 -> gh1T
__global__ __launch_bounds__(256) void k_p1(
    const u64* __restrict__ part, const float* __restrict__ emb,
    const u16* __restrict__ h0F, const u16* __restrict__ h1F,
    const u16* __restrict__ wih0F, const u16* __restrict__ whh0F, const u16* __restrict__ whh1F,
    const float* __restrict__ bih0, const float* __restrict__ bhh0, const float* __restrict__ bhh1,
    const float* __restrict__ h0T, float* __restrict__ h0Tn, u16* __restrict__ h0Fn,
    float* __restrict__ gh1T){
  __shared__ float lds[4*4*3*256];   // 48 KB
  __shared__ int tokL[64];
  const int tid = threadIdx.x, l = tid & 63, wv = tid >> 6, wg = blockIdx.x;
  if(wg < 64){
    if(tid < 64) tokL[tid] = (int)(0xFFFFFFFFu - (u32)(part[tid] & 0xFFFFFFFFull));
    __syncthreads();
    const int t = wg;
    f32x4 a0[4][3], ax[4][3];
    zacc<3>(a0, ax);
    // gi0 over K=512, this wave's ks chunk [wv*4, wv*4+4)
    for(int ks = wv*4; ks < wv*4+4; ++ks){
      h8 Ah[4], Al[4];
#pragma unroll
      for(int m=0;m<4;++m){
        const int b = m*16 + (l&15);
        const float* ep = emb + (size_t)tokL[b]*512 + ks*32 + (l>>4)*8;
        float4 u0 = *reinterpret_cast<const float4*>(ep);
        float4 u1 = *reinterpret_cast<const float4*>(ep + 4);
        float v[8] = { fmaxf(u0.x,0.f), fmaxf(u0.y,0.f), fmaxf(u0.z,0.f), fmaxf(u0.w,0.f),
                       fmaxf(u1.x,0.f), fmaxf(u1.y,0.f), fmaxf(u1.z,0.f), fmaxf(u1.w,0.f) };
        cvt8(v, Ah[m], Al[m]);
      }
#pragma unroll
      for(int g=0;g<3;++g){
        const u16* wb = wih0F + ((size_t)((g*64 + t)*16 + ks)*2)*512 + l*8;
        h8 Wh = *reinterpret_cast<const h8*>(wb);
        h8 Wl = *reinterpret_cast<const h8*>(wb + 512);
#pragma unroll
        for(int m=0;m<4;++m) mm3(Ah[m], Al[m], Wh, Wl, a0[m][g], ax[m][g]);
      }
    }
    to_lds<3>(lds, wv, l, a0, ax);
    __syncthreads();
    const int b = l;
    float gifin[4][3];
#pragma unroll
    for(int i=0;i<4;++i){
      const int c16 = wv + 4*i;
#pragma unroll
      for(int g=0;g<3;++g) gifin[i][g] = red4(lds, 3, b>>4, g, b&15, c16);
    }
    __syncthreads();
    // gh0 over K=1024, chunk [wv*8, wv*8+8)
    zacc<3>(a0, ax);
    gemm_run<3,64>(h0F, whh0F, t, wv*8, 8, l, a0, ax);
    to_lds<3>(lds, wv, l, a0, ax);
    __syncthreads();
#pragma unroll
    for(int i=0;i<4;++i){
      const int c16 = wv + 4*i;
      const int c = t*16 + c16;
      const float hr = red4(lds, 3, b>>4, 0, b&15, c16) + bhh0[c];
      const float hz = red4(lds, 3, b>>4, 1, b&15, c16) + bhh0[1024+c];
      const float hn = red4(lds, 3, b>>4, 2, b&15, c16) + bhh0[2048+c];
      const float ir = gifin[i][0] + bih0[c];
      const float iz = gifin[i][1] + bih0[1024+c];
      const float in_ = gifin[i][2] + bih0[2048+c];
      const float r = sig_(ir+hr), z = sig_(iz+hz);
      const float n = tanhf(in_ + r*hn);
      const float ho = h0T[c*64 + b];
      const float hv = (1.f-z)*n + z*ho;
      h0Tn[c*64 + b] = hv;
      store_frag(h0Fn, b, c, hv);
    }
  } else {
    const int t = wg - 64;
    f32x4 a0[4][3], ax[4][3];
    zacc<3>(a0, ax);
    gemm_run<3,64>(h1F, whh1F, t, wv*8, 8, l, a0, ax);
    to_lds<3>(lds, wv, l, a0, ax);
    __syncthreads();
    const int b = l;
#pragma unroll
    for(int i=0;i<4;++i){
      const int c16 = wv + 4*i;
      const int c = t*16 + c16;
#pragma unroll
      for(int g=0;g<3;++g){
        const float v = red4(lds, 3, b>>4, g, b&15, c16) + bhh1[g*1024 + c];
        gh1T[(size_t)(g*1024 + c)*64 + b] = v;
      }
    }
  }
}

// ---- P2: gi1 = h0n@Wih1^T ; combine with gh1T -> h1n ------------------------
__global__ __launch_bounds__(256) void k_p2(
    const u16* __restrict__ h0Fn, const float* __restrict__ gh1T,
    const u16* __restrict__ wih1F, const float* __restrict__ bih1,
    const float* __restrict__ h1T, float* __restrict__ h1Tn, u16* __restrict__ h1Fn){
  __shared__ float lds[4*4*3*256];
  const int tid = threadIdx.x, l = tid & 63, wv = tid >> 6, t = blockIdx.x;
  f32x4 a0[4][3], ax[4][3];
  zacc<3>(a0, ax);
  gemm_run<3,64>(h0Fn, wih1F, t, wv*8, 8, l, a0, ax);
  to_lds<3>(lds, wv, l, a0, ax);
  __syncthreads();
  const int b = l;
#pragma unroll
  for(int i=0;i<4;++i){
    const int c16 = wv + 4*i;
    const int c = t*16 + c16;
    const float ir = red4(lds, 3, b>>4, 0, b&15, c16) + bih1[c];
    const float iz = red4(lds, 3, b>>4, 1, b&15, c16) + bih1[1024+c];
    const float in_ = red4(lds, 3, b>>4, 2, b&15, c16) + bih1[2048+c];
    const float hr = gh1T[(size_t)(0*1024 + c)*64 + b];
    const float hz = gh1T[(size_t)(1*1024 + c)*64 + b];
    const float hn = gh1T[(size_t)(2*1024 + c)*64 + b];
    const float r = sig_(ir+hr), z = sig_(iz+hz);
    const float n = tanhf(in_ + r*hn);
    const float ho = h1T[c*64 + b];
    const float hv = (1.f-z)*n + z*ho;
    h1Tn[c*64 + b] = hv;
    store_frag(h1Fn, b, c, hv);
  }
}

// ---- P3: hid = relu(h1n@pW1^T + pb1) ; resets argmax accumulator ------------
__global__ __launch_bounds__(256) void k_p3(
    const u16* __restrict__ h1Fn, const u16* __restrict__ pw1F,
    const float* __restrict__ pb1, u16* __restrict__ hidF, u64* __restrict__ part){
  __shared__ float lds[4*4*4*256];   // 64 KB
  const int tid = threadIdx.x, l = tid & 63, wv = tid >> 6, t = blockIdx.x;
  if(blockIdx.x == 0 && tid < 64) part[tid] = 0ull;
  f32x4 a0[4][4], ax[4][4];
  zacc<4>(a0, ax);
  gemm_run<4,1>(h1Fn, pw1F, t*4, wv*8, 8, l, a0, ax);
  to_lds<4>(lds, wv, l, a0, ax);
  __syncthreads();
  const int b = l;
#pragma unroll
  for(int i=0;i<16;++i){
    const int col = wv + 4*i;
    const int c = t*64 + col;
    const float v = red4(lds, 4, b>>4, col>>4, b&15, col&15) + pb1[c];
    store_frag(hidF, b, c, fmaxf(v, 0.f));
  }
}

// ---- P4: logits = hid@pW2^T + pb2 ; store out ; argmax -> part --------------
__global__ __launch_bounds__(256) void k_p4(
    const u16* __restrict__ hidF, const u16* __restrict__ pw2F,
    const float* __restrict__ pb2, float* __restrict__ out,
    u64* __restrict__ part, int step){
  __shared__ float lds[4*4*4*256];
  const int tid = threadIdx.x, l = tid & 63, wv = tid >> 6, v0 = blockIdx.x;
  const int c0 = v0*64;
  f32x4 a0[4][4], ax[4][4];
  zacc<4>(a0, ax);
  gemm_run<4,1>(hidF, pw2F, v0*4, wv*8, 8, l, a0, ax);
  to_lds<4>(lds, wv, l, a0, ax);
  __syncthreads();
#pragma unroll
  for(int i=0;i<16;++i){
    const int row = wv + 4*i;           // batch
    const int col = l;
    const int c = c0 + col;
    float s = red4(lds, 4, row>>4, col>>4, row&15, col&15);
    u64 p = 0ull;
    if(c < V_){
      s += pb2[c];
      out[((size_t)row*T_ + step)*V_ + c] = s;
      u32 kb = __float_as_uint(s);
      kb = (kb & 0x80000000u) ? ~kb : (kb | 0x80000000u);
      p = ((u64)kb << 32) | (u64)(0xFFFFFFFFu - (u32)c);
    }
#pragma unroll
    for(int d=1; d<64; d<<=1){
      const u64 o = __shfl_xor(p, d, 64);
      if(o > p) p = o;
    }
    if(l == 0) atomicMax(&part[row], p);
  }
}

extern "C" void kernel_launch(void* const* d_in, const int* in_sizes, int n_in,
                              void* d_out, int out_size, void* d_ws, size_t ws_size,
                              hipStream_t stream) {
  (void)in_sizes; (void)n_in; (void)out_size;
  const float* efs  = (const float*)d_in[1];
  const float* embW = (const float*)d_in[2];
  const float* Wih0 = (const float*)d_in[3];
  const float* Whh0 = (const float*)d_in[4];
  const float* bih0 = (const float*)d_in[5];
  const float* bhh0 = (const float*)d_in[6];
  const float* Wih1 = (const float*)d_in[7];
  const float* Whh1 = (const float*)d_in[8];
  const float* bih1 = (const float*)d_in[9];
  const float* bhh1 = (const float*)d_in[10];
  const float* pW1  = (const float*)d_in[11];
  const float* pb1  = (const float*)d_in[12];
  const float* pW2  = (const float*)d_in[13];
  const float* pb2  = (const float*)d_in[14];
  float* out = (float*)d_out;

  // ws layout (bytes)
  const size_t o_wih0F = 0;          // 192t x 16ks x 2KB = 6,291,456
  const size_t o_whh0F = 6291456;    // 192 x 32 = 12,582,912
  const size_t o_whh1F = 18874368;
  const size_t o_wih1F = 31457280;
  const size_t o_pw1F  = 44040192;   // 64 x 32 = 4,194,304
  const size_t o_pw2F  = 48234496;   // 628 x 32 = 41,156,608
  const size_t o_h0Fa  = 89391104;   // act frag buffers: 262,144 each
  const size_t o_h0Fb  = 89653248;
  const size_t o_h1Fa  = 89915392;
  const size_t o_h1Fb  = 90177536;
  const size_t o_hidF  = 90439680;
  const size_t o_h0Ta  = 90701824;   // f32 mirrors [c][b]: 262,144 each
  const size_t o_h0Tb  = 90963968;
  const size_t o_h1Ta  = 91226112;
  const size_t o_h1Tb  = 91488256;
  const size_t o_gh1T  = 91750400;   // 786,432
  const size_t o_part  = 92536832;   // 512
  const size_t need    = 92537344;
  if(ws_size < need) return;         // loud zero-output failure (diagnostic)

  char* ws = (char*)d_ws;
  u16* wih0F = (u16*)(ws + o_wih0F);
  u16* whh0F = (u16*)(ws + o_whh0F);
  u16* whh1F = (u16*)(ws + o_whh1F);
  u16* wih1F = (u16*)(ws + o_wih1F);
  u16* pw1F  = (u16*)(ws + o_pw1F);
  u16* pw2F  = (u16*)(ws + o_pw2F);
  u16* h0Fa  = (u16*)(ws + o_h0Fa);
  u16* h0Fb  = (u16*)(ws + o_h0Fb);
  u16* h1Fa  = (u16*)(ws + o_h1Fa);
  u16* h1Fb  = (u16*)(ws + o_h1Fb);
  u16* hidF  = (u16*)(ws + o_hidF);
  float* h0Ta = (float*)(ws + o_h0Ta);
  float* h0Tb = (float*)(ws + o_h0Tb);
  float* h1Ta = (float*)(ws + o_h1Ta);
  float* h1Tb = (float*)(ws + o_h1Tb);
  float* gh1T = (float*)(ws + o_gh1T);
  u64*   part = (u64*)(ws + o_part);

  // one-time weight fragment conversion (graph nodes, re-run each launch: deterministic)
  k_wcvt<<<dim3(768),  dim3(256), 0, stream>>>(Wih0, 3072, 512, 16, wih0F);
  k_wcvt<<<dim3(1536), dim3(256), 0, stream>>>(Whh0, 3072, 1024, 32, whh0F);
  k_wcvt<<<dim3(1536), dim3(256), 0, stream>>>(Whh1, 3072, 1024, 32, whh1F);
  k_wcvt<<<dim3(1536), dim3(256), 0, stream>>>(Wih1, 3072, 1024, 32, wih1F);
  k_wcvt<<<dim3(512),  dim3(256), 0, stream>>>(pW1, 1024, 1024, 32, pw1F);
  k_wcvt<<<dim3(5024), dim3(256), 0, stream>>>(pW2, V_, 1024, 32, pw2F);
  k_init<<<dim3(256),  dim3(256), 0, stream>>>(efs, h0Ta, h1Ta, h0Fa, h1Fa, part);

  for(int t = 0; t < T_; ++t){
    const u16*  h0Fc = (t & 1) ? h0Fb : h0Fa;
    u16*        h0Fn = (t & 1) ? h0Fa : h0Fb;
    const u16*  h1Fc = (t & 1) ? h1Fb : h1Fa;
    u16*        h1Fn = (t & 1) ? h1Fa : h1Fb;
    const float* h0Tc = (t & 1) ? h0Tb : h0Ta;
    float*       h0Tn = (t & 1) ? h0Ta : h0Tb;
    const float* h1Tc = (t & 1) ? h1Tb : h1Ta;
    float*       h1Tn = (t & 1) ? h1Ta : h1Tb;
    k_p1<<<dim3(128), dim3(256), 0, stream>>>(part, embW, h0Fc, h1Fc, wih0F, whh0F, whh1F,
                                              bih0, bhh0, bhh1, h0Tc, h0Tn, h0Fn, gh1T);
    k_p2<<<dim3(64),  dim3(256), 0, stream>>>(h0Fn, gh1T, wih1F, bih1, h1Tc, h1Tn, h1Fn);
    k_p3<<<dim3(16),  dim3(256), 0, stream>>>(h1Fn, pw1F, pb1, hidF, part);
    k_p4<<<dim3(157), dim3(256), 0, stream>>>(hidF, pw2F, pb2, out, part, t);
  }
}